// Round 6
// baseline (132.814 us; speedup 1.0000x reference)
//
#include <hip/hip_runtime.h>
#include <math.h>

#define ALPHA 0.2f
#define LOG2E 1.4426950408889634f

constexpr int B = 32, N = 1024, C = 64;

typedef __attribute__((ext_vector_type(8))) short short8;
typedef __attribute__((ext_vector_type(4))) float floatx4;

// round-half-up bf16 (err <= 0.5 ulp; ties differ from RNE only)
static __device__ __forceinline__ unsigned bfu(float f) {
    return (__float_as_uint(f) + 0x8000u) >> 16;
}
static __device__ __forceinline__ unsigned pk2(float lo, float hi) {
    return ((__float_as_uint(hi) + 0x8000u) & 0xFFFF0000u) |
           ((__float_as_uint(lo) + 0x8000u) >> 16);
}

// ---------------- K1: blocks<1024: adj -> bitmask
//                  blocks>=1024: input->bf16 cvt + exact s vectors ----------
__global__ __launch_bounds__(256) void gat_pre(
    const float* __restrict__ input, const float* __restrict__ adj,
    const float* __restrict__ Wm, const float* __restrict__ a,
    unsigned short* __restrict__ inbf, float* __restrict__ ssrc,
    float* __restrict__ sdst, unsigned long long* __restrict__ mask64)
{
    const int tid = threadIdx.x, lane = tid & 63, wave = tid >> 6;

    if (blockIdx.x < 1024) {                        // ---- mask blocks ----
        const int mb = blockIdx.x;
#pragma unroll
        for (int t = 0; t < 4; ++t) {
            const int id = mb * 16 + wave * 4 + t;  // 0..16383
            const int i = id >> 4, jc = id & 15;
            const float av = adj[(size_t)i * N + jc * 64 + lane];
            const unsigned long long bal = __ballot(av > 0.5f);
            if (lane == 0) mask64[i * 16 + jc] = bal;
        }
        return;
    }

    __shared__ float wa_l[128];
    const int r0 = (blockIdx.x - 1024) * 32;

    // wa[k] = sum_c W[k][c] * a_{src,dst}[c]  (exact fp32)
    if (tid < 128) {
        const int k = tid & 63, half = tid >> 6;
        const float* __restrict__ ar = a + half * 64;
        const float* __restrict__ wr = Wm + k * 64;
        float acc = 0.f;
#pragma unroll
        for (int c4 = 0; c4 < 16; ++c4) {
            const float4 wv = *(const float4*)&wr[c4 * 4];
            const float4 av = *(const float4*)&ar[c4 * 4];
            acc = fmaf(wv.x, av.x, fmaf(wv.y, av.y, fmaf(wv.z, av.z, fmaf(wv.w, av.w, acc))));
        }
        wa_l[half * 64 + k] = acc;
    }

    // input -> bf16 (rows r0..r0+31)
    {
        const float* __restrict__ src = input + (size_t)r0 * 64 + tid * 8;
        const float4 v0 = *(const float4*)src;
        const float4 v1 = *(const float4*)(src + 4);
        uint4 o;
        o.x = pk2(v0.x, v0.y); o.y = pk2(v0.z, v0.w);
        o.z = pk2(v1.x, v1.y); o.w = pk2(v1.z, v1.w);
        *(uint4*)&inbf[(size_t)r0 * 64 + tid * 8] = o;
    }
    __syncthreads();

    // s vectors: 8 threads per row, exact fp32, pre-scaled by log2(e)
    {
        const int row = r0 + (tid >> 3), seg = tid & 7;
        const float4 x0 = *(const float4*)&input[(size_t)row * 64 + seg * 8];
        const float4 x1 = *(const float4*)&input[(size_t)row * 64 + seg * 8 + 4];
        float vs = 0.f, vd = 0.f;
        const float4 w0 = *(const float4*)&wa_l[seg * 8];
        const float4 w1 = *(const float4*)&wa_l[seg * 8 + 4];
        const float4 d0 = *(const float4*)&wa_l[64 + seg * 8];
        const float4 d1 = *(const float4*)&wa_l[64 + seg * 8 + 4];
        vs = fmaf(x0.x, w0.x, fmaf(x0.y, w0.y, fmaf(x0.z, w0.z, fmaf(x0.w, w0.w, vs))));
        vs = fmaf(x1.x, w1.x, fmaf(x1.y, w1.y, fmaf(x1.z, w1.z, fmaf(x1.w, w1.w, vs))));
        vd = fmaf(x0.x, d0.x, fmaf(x0.y, d0.y, fmaf(x0.z, d0.z, fmaf(x0.w, d0.w, vd))));
        vd = fmaf(x1.x, d1.x, fmaf(x1.y, d1.y, fmaf(x1.z, d1.z, fmaf(x1.w, d1.w, vd))));
        vs += __shfl_xor(vs, 1, 64); vd += __shfl_xor(vd, 1, 64);
        vs += __shfl_xor(vs, 2, 64); vd += __shfl_xor(vd, 2, 64);
        vs += __shfl_xor(vs, 4, 64); vd += __shfl_xor(vd, 4, 64);
        if (seg == 0) { ssrc[row] = vs * LOG2E; sdst[row] = vd * LOG2E; }
    }
}

// ---------------- K2: fused h-MFMA + softmax(exp2, no-shift) + PV-MFMA + ELU
// One barrier per j-tile (double-buffered h_u/p_u); all global loads reg-level.
__global__ __launch_bounds__(256) void gat_attn(
    const unsigned short* __restrict__ inbf, const float* __restrict__ Wm,
    const float* __restrict__ ssrc, const float* __restrict__ sdst,
    const unsigned char* __restrict__ maskB, float* __restrict__ out)
{
    __shared__ __align__(16) unsigned short h_u[2][64 * 64];  // 16 KB swizzled [c][j]
    __shared__ __align__(16) unsigned short p_u[2][32 * 64];  // 8 KB swizzled [i][j]
    __shared__ __align__(16) float sd_l[1024];                // 4 KB
    __shared__ float psum_s[32];

    const int tid = threadIdx.x, lane = tid & 63, wave = tid >> 6;
    const int b = blockIdx.x & 31;
    const int i0 = (blockIdx.x >> 5) * 32;

    ((float4*)sd_l)[tid] = ((const float4*)(sdst + b * N))[tid];

    // --- p role: row ii, j-octet jo ---
    const int ii = tid >> 3, jo = tid & 7;
    const float ssq = ssrc[b * N + i0 + ii];
    const unsigned char* __restrict__ mrow = maskB + (size_t)(i0 + ii) * 128;
    unsigned mreg[4];
#pragma unroll
    for (int q = 0; q < 4; ++q) {
        unsigned v = 0;
#pragma unroll
        for (int t = 0; t < 4; ++t)
            v |= (unsigned)mrow[(q * 4 + t) * 8 + jo] << (t * 8);
        mreg[q] = v;
    }

    // --- MFMA role ---
    const int n16 = lane & 15, kq = lane >> 4;
    const int cB = wave * 16 + n16;                 // this wave's c column
    const unsigned short* __restrict__ Ab = inbf + (size_t)b * 1024 * 64;

    // W B-frags (const over tiles): wf[kc][e] = W[kc*32+kq*8+e][cB]
    short8 wf[2];
#pragma unroll
    for (int kc = 0; kc < 2; ++kc)
#pragma unroll
        for (int e = 0; e < 8; ++e)
            wf[kc][e] = (short)bfu(Wm[(kc * 32 + kq * 8 + e) * 64 + cB]);

    // swizzled LDS offsets (halfword units)
    const int pwoff = ii * 64 + (jo ^ (ii & 7)) * 8;
    int hwo[4];                                     // h_u write slot per msub
#pragma unroll
    for (int ms = 0; ms < 4; ++ms)
        hwo[ms] = cB * 64 + (((ms * 2 + (kq >> 1)) ^ (cB & 7)) * 8) + (kq & 1) * 4;

    auto loadA = [&](int jt, short8 af[4][2]) {
#pragma unroll
        for (int ms = 0; ms < 4; ++ms)
#pragma unroll
            for (int kc = 0; kc < 2; ++kc)
                af[ms][kc] = *(const short8*)&Ab[(size_t)(jt * 64 + ms * 16 + n16) * 64 + kc * 32 + kq * 8];
    };

    floatx4 acc0 = {0.f,0.f,0.f,0.f}, acc1 = {0.f,0.f,0.f,0.f};
    float psacc = 0.f;
    short8 afn[4][2];
    loadA(0, afn);
    __syncthreads();                                // sd_l ready

#pragma unroll 2
    for (int jt = 0; jt < 16; ++jt) {
        const int buf = jt & 1;
        short8 afc[4][2];
#pragma unroll
        for (int ms = 0; ms < 4; ++ms) { afc[ms][0] = afn[ms][0]; afc[ms][1] = afn[ms][1]; }
        if (jt < 15) loadA(jt + 1, afn);            // reg prefetch, vmcnt-tracked

        // --- h tile: D[j][c] = inbf[j][:] @ W[:][cB], write as [c][j] ---
#pragma unroll
        for (int ms = 0; ms < 4; ++ms) {
            floatx4 ha = {0.f,0.f,0.f,0.f};
            ha = __builtin_amdgcn_mfma_f32_16x16x32_bf16(afc[ms][0], wf[0], ha, 0, 0, 0);
            ha = __builtin_amdgcn_mfma_f32_16x16x32_bf16(afc[ms][1], wf[1], ha, 0, 0, 0);
            const uint2 hv = {pk2(ha[0], ha[1]), pk2(ha[2], ha[3])};
            *(uint2*)&h_u[buf][hwo[ms]] = hv;
        }

        // --- p tile ---
        {
            const unsigned mb = (mreg[jt >> 2] >> ((jt & 3) * 8)) & 0xffu;
            const float4 s0 = *(const float4*)&sd_l[jt * 64 + jo * 8];
            const float4 s1 = *(const float4*)&sd_l[jt * 64 + jo * 8 + 4];
            const float ev[8] = {s0.x, s0.y, s0.z, s0.w, s1.x, s1.y, s1.z, s1.w};
            float p[8];
            float loc = 0.f;
#pragma unroll
            for (int k = 0; k < 8; ++k) {
                float t = ssq + ev[k];
                t = fmaxf(t, ALPHA * t);            // leaky-relu
                p[k] = ((mb >> k) & 1u) ? exp2f(t) : 0.f;
                loc += p[k];
            }
            psacc += loc;
            const uint4 pw = {pk2(p[0], p[1]), pk2(p[2], p[3]), pk2(p[4], p[5]), pk2(p[6], p[7])};
            *(uint4*)&p_u[buf][pwoff] = pw;
        }

        __syncthreads();                            // tile visible to all waves

        // --- PV ---
#pragma unroll
        for (int kc = 0; kc < 2; ++kc) {
            const int ch = (kc * 4 + kq);
            const short8 bfr = *(const short8*)&h_u[buf][cB * 64 + ((ch ^ (cB & 7)) * 8)];
            const short8 a0  = *(const short8*)&p_u[buf][n16 * 64 + ((ch ^ (n16 & 7)) * 8)];
            const short8 a1  = *(const short8*)&p_u[buf][(16 + n16) * 64 + ((ch ^ (n16 & 7)) * 8)];
            acc0 = __builtin_amdgcn_mfma_f32_16x16x32_bf16(a0, bfr, acc0, 0, 0, 0);
            acc1 = __builtin_amdgcn_mfma_f32_16x16x32_bf16(a1, bfr, acc1, 0, 0, 0);
        }
    }

    psacc += __shfl_xor(psacc, 1, 64);
    psacc += __shfl_xor(psacc, 2, 64);
    psacc += __shfl_xor(psacc, 4, 64);
    if (jo == 0) psum_s[ii] = psacc;
    __syncthreads();

#pragma unroll
    for (int it = 0; it < 2; ++it) {
        const floatx4 acc = it ? acc1 : acc0;
#pragma unroll
        for (int r = 0; r < 4; ++r) {
            const int row = it * 16 + kq * 4 + r;   // C/D: col=lane&15, row=kq*4+r
            const float hp = acc[r] / psum_s[row];
            const float o = hp > 0.f ? hp : __expf(hp) - 1.f;
            out[((size_t)(b * N + i0 + row)) * 64 + cB] = o;
        }
    }
}

extern "C" void kernel_launch(void* const* d_in, const int* in_sizes, int n_in,
                              void* d_out, int out_size, void* d_ws, size_t ws_size,
                              hipStream_t stream) {
    const float* input = (const float*)d_in[0];
    const float* adj   = (const float*)d_in[1];
    const float* Wm    = (const float*)d_in[2];
    const float* a     = (const float*)d_in[3];
    float* out = (float*)d_out;

    char* ws = (char*)d_ws;
    unsigned short* inbf = (unsigned short*)ws;                                 // 4 MB
    float* ssrc = (float*)(ws + 4194304);                                       // 128 KB
    float* sdst = (float*)(ws + 4194304 + 131072);                              // 128 KB
    unsigned long long* mask64 = (unsigned long long*)(ws + 4194304 + 2 * 131072); // 128 KB

    gat_pre<<<2048, 256, 0, stream>>>(input, adj, Wm, a, inbf, ssrc, sdst, mask64);
    gat_attn<<<1024, 256, 0, stream>>>(inbf, Wm, ssrc, sdst, (const unsigned char*)mask64, out);
}

// Round 7
// 110.389 us; speedup vs baseline: 1.2031x; 1.2031x over previous
//
#include <hip/hip_runtime.h>
#include <math.h>

#define ALPHA 0.2f
#define LOG2E 1.4426950408889634f

constexpr int B = 32, N = 1024, C = 64;

typedef __attribute__((ext_vector_type(8))) short short8;
typedef __attribute__((ext_vector_type(16))) float floatx16;

// round-half-up bf16
static __device__ __forceinline__ unsigned bfu(float f) {
    return (__float_as_uint(f) + 0x8000u) >> 16;
}
static __device__ __forceinline__ unsigned pk2(float lo, float hi) {
    return ((__float_as_uint(hi) + 0x8000u) & 0xFFFF0000u) |
           ((__float_as_uint(lo) + 0x8000u) >> 16);
}

// ---------------- K1: three block classes -------------------------------
//  [0,1024)    : adj -> 64-bit masks
//  [1024,2048) : exact fp32 s vectors (pre-scaled by log2 e)
//  [2048,2176) : hT(bf16)[b*64+c][j] = (input @ W)^T via 32x32x16 MFMA
__global__ __launch_bounds__(256) void gat_pre(
    const float* __restrict__ input, const float* __restrict__ adj,
    const float* __restrict__ Wm, const float* __restrict__ a,
    unsigned short* __restrict__ hT, float* __restrict__ ssrc,
    float* __restrict__ sdst, unsigned long long* __restrict__ mask64)
{
    const int tid = threadIdx.x, lane = tid & 63, wave = tid >> 6;

    if (blockIdx.x < 1024) {                        // ---- mask blocks ----
        const int mb = blockIdx.x;
#pragma unroll
        for (int t = 0; t < 4; ++t) {
            const int id = mb * 16 + wave * 4 + t;  // 0..16383
            const int i = id >> 4, jc = id & 15;
            const float av = adj[(size_t)i * N + jc * 64 + lane];
            const unsigned long long bal = __ballot(av > 0.5f);
            if (lane == 0) mask64[i * 16 + jc] = bal;
        }
        return;
    }

    if (blockIdx.x < 2048) {                        // ---- s-vector blocks ----
        __shared__ float wa_l[128];
        const int r0 = (blockIdx.x - 1024) * 32;

        if (tid < 128) {                            // wa[k] = sum_c W[k][c]*a[c]
            const int k = tid & 63, half = tid >> 6;
            const float* __restrict__ ar = a + half * 64;
            const float* __restrict__ wr = Wm + k * 64;
            float acc = 0.f;
#pragma unroll
            for (int c4 = 0; c4 < 16; ++c4) {
                const float4 wv = *(const float4*)&wr[c4 * 4];
                const float4 av = *(const float4*)&ar[c4 * 4];
                acc = fmaf(wv.x, av.x, fmaf(wv.y, av.y, fmaf(wv.z, av.z, fmaf(wv.w, av.w, acc))));
            }
            wa_l[half * 64 + k] = acc;
        }
        __syncthreads();

        const int row = r0 + (tid >> 3), seg = tid & 7;
        const float4 x0 = *(const float4*)&input[(size_t)row * 64 + seg * 8];
        const float4 x1 = *(const float4*)&input[(size_t)row * 64 + seg * 8 + 4];
        float vs = 0.f, vd = 0.f;
        const float4 w0 = *(const float4*)&wa_l[seg * 8];
        const float4 w1 = *(const float4*)&wa_l[seg * 8 + 4];
        const float4 d0 = *(const float4*)&wa_l[64 + seg * 8];
        const float4 d1 = *(const float4*)&wa_l[64 + seg * 8 + 4];
        vs = fmaf(x0.x, w0.x, fmaf(x0.y, w0.y, fmaf(x0.z, w0.z, fmaf(x0.w, w0.w, vs))));
        vs = fmaf(x1.x, w1.x, fmaf(x1.y, w1.y, fmaf(x1.z, w1.z, fmaf(x1.w, w1.w, vs))));
        vd = fmaf(x0.x, d0.x, fmaf(x0.y, d0.y, fmaf(x0.z, d0.z, fmaf(x0.w, d0.w, vd))));
        vd = fmaf(x1.x, d1.x, fmaf(x1.y, d1.y, fmaf(x1.z, d1.z, fmaf(x1.w, d1.w, vd))));
        vs += __shfl_xor(vs, 1, 64); vd += __shfl_xor(vd, 1, 64);
        vs += __shfl_xor(vs, 2, 64); vd += __shfl_xor(vd, 2, 64);
        vs += __shfl_xor(vs, 4, 64); vd += __shfl_xor(vd, 4, 64);
        if (seg == 0) { ssrc[row] = vs * LOG2E; sdst[row] = vd * LOG2E; }
        return;
    }

    // ---- hT blocks: D[c][j] = W^T @ input^T (per b), 32x32x16 MFMA ----
    {
        const int hb = blockIdx.x - 2048;           // 0..127
        const int b  = hb >> 2;
        const int j0 = (hb & 3) * 256;
        const int wc = wave & 1, ws = wave >> 1;
        const int n32 = lane & 31, kh = lane >> 5;

        // A = W^T: A[m=c][k]: frag element e = W[(q*16+kh*8+e)*64 + wc*32+n32]
        short8 wfr[4];
#pragma unroll
        for (int q = 0; q < 4; ++q)
#pragma unroll
            for (int e = 0; e < 8; ++e)
                wfr[q][e] = (short)bfu(Wm[(q * 16 + kh * 8 + e) * 64 + wc * 32 + n32]);

        const float* __restrict__ inb = input + (size_t)b * 1024 * 64;

#pragma unroll
        for (int tt = 0; tt < 4; ++tt) {
            const int jb = j0 + ws * 128 + tt * 32;
            floatx16 acc = {};
#pragma unroll
            for (int q = 0; q < 4; ++q) {
                const float4 x0 = *(const float4*)&inb[(size_t)(jb + n32) * 64 + q * 16 + kh * 8];
                const float4 x1 = *(const float4*)&inb[(size_t)(jb + n32) * 64 + q * 16 + kh * 8 + 4];
                union { uint4 u; short8 s; } bf;
                bf.u.x = pk2(x0.x, x0.y); bf.u.y = pk2(x0.z, x0.w);
                bf.u.z = pk2(x1.x, x1.y); bf.u.w = pk2(x1.z, x1.w);
                acc = __builtin_amdgcn_mfma_f32_32x32x16_bf16(wfr[q], bf.s, acc, 0, 0, 0);
            }
#pragma unroll
            for (int r = 0; r < 16; ++r) {
                const int rc = (r & 3) + 8 * (r >> 2) + 4 * kh;   // c offset
                hT[((size_t)(b * 64 + wc * 32 + rc)) * 1024 + jb + n32] = (unsigned short)bfu(acc[r]);
            }
        }
    }
}

// ---------------- K2: barrier-free fused softmax + PV (32x32x16 MFMA) ------
// Wave = (b, i-tile 32, c-half, j-half). A-frags (p) computed in-register by
// the consuming lane; B-frags straight from L2-hot hT. One barrier total.
__global__ __launch_bounds__(256, 4) void gat_attn(
    const unsigned short* __restrict__ hTg, const float* __restrict__ ssrc,
    const float* __restrict__ sdst, const unsigned long long* __restrict__ mask64,
    float* __restrict__ out)
{
    __shared__ __align__(16) float accb[2][16 * 64];   // 8 KB
    __shared__ float psum_s[4 * 32];

    const int tid = threadIdx.x, lane = tid & 63, wave = tid >> 6;
    const int b  = blockIdx.x & 31;
    const int i0 = (blockIdx.x >> 5) * 32;
    const int wc = wave & 1;                       // c-half
    const int wj = wave >> 1;                      // j-half
    const int c0 = wc * 32;
    const int n32 = lane & 31, kh = lane >> 5;

    const float ssq = ssrc[b * N + i0 + n32];      // row of A this lane owns
    const float* __restrict__ sdb = sdst + b * N;
    const unsigned short* __restrict__ hTb = hTg + ((size_t)(b * 64 + c0 + n32)) * 1024;
    const unsigned long long* __restrict__ mrow = mask64 + (size_t)(i0 + n32) * 16;

    floatx16 acc = {};
    float psacc = 0.f;

    for (int t = 0; t < 8; ++t) {
        const int jt = wj * 8 + t;
        const int jb = jt * 64;

        short8 hfr[4];
        float4 sa[4], sb[4];
#pragma unroll
        for (int q = 0; q < 4; ++q) {
            hfr[q] = *(const short8*)&hTb[jb + q * 16 + kh * 8];         // B-frag (L2)
            sa[q]  = *(const float4*)&sdb[jb + q * 16 + kh * 8];         // broadcast
            sb[q]  = *(const float4*)&sdb[jb + q * 16 + kh * 8 + 4];
        }
        const uint2 mw = *(const uint2*)&mrow[jt];

#pragma unroll
        for (int q = 0; q < 4; ++q) {
            const unsigned mword = (q < 2) ? mw.x : mw.y;
            const unsigned msh = mword >> ((q & 1) * 16 + kh * 8);
            const float sv[8] = {sa[q].x, sa[q].y, sa[q].z, sa[q].w,
                                 sb[q].x, sb[q].y, sb[q].z, sb[q].w};
            float p[8];
#pragma unroll
            for (int e = 0; e < 8; ++e) {
                float tv = ssq + sv[e];
                tv = fmaxf(tv, ALPHA * tv);                  // leaky-relu (log2 domain)
                tv = ((msh >> e) & 1u) ? tv : -200.f;        // mask -> exp2 = 0
                p[e] = exp2f(tv);
                psacc += p[e];
            }
            union { uint4 u; short8 s; } af;
            af.u.x = pk2(p[0], p[1]); af.u.y = pk2(p[2], p[3]);
            af.u.z = pk2(p[4], p[5]); af.u.w = pk2(p[6], p[7]);
            acc = __builtin_amdgcn_mfma_f32_32x32x16_bf16(af.s, hfr[q], acc, 0, 0, 0);
        }
    }

    // merge: psum across kh halves; acc + psum across j-halves via LDS
    psacc += __shfl_xor(psacc, 32, 64);
    if (lane < 32) psum_s[wave * 32 + lane] = psacc;
    if (wj == 1) {
#pragma unroll
        for (int r = 0; r < 16; ++r) accb[wc][r * 64 + lane] = acc[r];
    }
    __syncthreads();

    if (wj == 0) {
#pragma unroll
        for (int r = 0; r < 16; ++r) {
            const float sum = acc[r] + accb[wc][r * 64 + lane];
            const int row = (r & 3) + 8 * (r >> 2) + 4 * kh;   // C/D row map
            const float ps = psum_s[row] + psum_s[64 + row];    // waves 0 + 2
            const float hp = sum / ps;
            const float o = hp > 0.f ? hp : __expf(hp) - 1.f;
            out[((size_t)(b * N + i0 + row)) * 64 + c0 + n32] = o;
        }
    }
}

extern "C" void kernel_launch(void* const* d_in, const int* in_sizes, int n_in,
                              void* d_out, int out_size, void* d_ws, size_t ws_size,
                              hipStream_t stream) {
    const float* input = (const float*)d_in[0];
    const float* adj   = (const float*)d_in[1];
    const float* Wm    = (const float*)d_in[2];
    const float* a     = (const float*)d_in[3];
    float* out = (float*)d_out;

    char* ws = (char*)d_ws;
    unsigned short* hT = (unsigned short*)ws;                                      // 4 MB
    float* ssrc = (float*)(ws + 4194304);                                          // 128 KB
    float* sdst = (float*)(ws + 4194304 + 131072);                                 // 128 KB
    unsigned long long* mask64 = (unsigned long long*)(ws + 4194304 + 2 * 131072); // 128 KB

    gat_pre<<<2176, 256, 0, stream>>>(input, adj, Wm, a, hT, ssrc, sdst, mask64);
    gat_attn<<<1024, 256, 0, stream>>>(hT, ssrc, sdst, mask64, out);
}